// Round 4
// baseline (258.263 us; speedup 1.0000x reference)
//
#include <hip/hip_runtime.h>
#include <math.h>

// fft_coeffs: (32, 6, 384, 384) fp32; kernel: (3,1,21,21) fp32 uniform box.
//   out ch 0-2: log1p(mag) - boxfilter21x21(log1p(mag)) * w_c  (zero-padded)
//   out ch 3-5: copy.
// Separable box filter; sliding-window in 8-output segments for ILP + full
// wave utilization (R3 was latency-bound: 32-deep serial chains on 128 thr).
#define HH    384
#define WW    384
#define TILE   64
#define HALO   10
#define KW     21
#define LDIM   84          // TILE + 2*HALO
#define LMS    85          // lm row stride (pad)
#define HSS    65          // hs row stride (pad)
#define SEG     8          // outputs per sliding task
#define PLANE 147456       // 384*384

__global__ __launch_bounds__(256)
void spectral_residual_fused_kernel(const float* __restrict__ in,
                                    const float* __restrict__ kern,
                                    float* __restrict__ out)
{
    __shared__ float lm[LDIM * LMS];   // 84x85 log tile   (28.6 KB)
    __shared__ float hs[LDIM * HSS];   // 84x65 horiz sums (21.8 KB)

    const int tid   = threadIdx.x;
    const int tx    = blockIdx.x;
    const int ty    = blockIdx.y;
    const int plane = blockIdx.z;          // n*6 + c
    const int c     = plane % 6;
    const size_t plane_off = (size_t)plane * PLANE;

    if (c >= 3) {
        // Phase channels: contiguous 16 KB float4 copy per block.
        const float4* __restrict__ s = (const float4*)(in + plane_off);
        float4*       __restrict__ d = (float4*)(out + plane_off);
        const int base = (ty * 6 + tx) * 1024;
        #pragma unroll
        for (int i = 0; i < 4; ++i) {
            int e = base + i * 256 + tid;
            d[e] = s[e];
        }
        return;
    }

    const float w = kern[c * (KW * KW)];   // uniform weight (1/441)

    const float* __restrict__ src = in  + plane_off;
    float*       __restrict__ dst = out + plane_off;

    const int gy0 = ty * TILE - HALO;
    const int gx0 = tx * TILE - HALO;

    // ---- Stage log(1+mag) halo tile (zero-pad OOB). x in [0,1] -> 1+x in
    // [1,2]: __logf is accurate there (~1e-7 abs). ----
    for (int idx = tid; idx < LDIM * LDIM; idx += 256) {
        int r   = idx / LDIM;
        int col = idx - r * LDIM;
        int gy  = gy0 + r;
        int gx  = gx0 + col;
        float v = 0.0f;
        if (gy >= 0 && gy < HH && gx >= 0 && gx < WW)
            v = __logf(1.0f + src[gy * WW + gx]);
        lm[r * LMS + col] = v;
    }
    __syncthreads();

    // ---- Horizontal 21-sums in 8-output sliding segments.
    // 84 rows x 8 segs = 672 tasks; 4-accumulator init (chain depth ~6). ----
    for (int t = tid; t < LDIM * SEG; t += 256) {
        const int r  = t >> 3;
        const int x0 = (t & 7) * SEG;
        const float* row  = &lm[r * LMS + x0];
        float*       hrow = &hs[r * HSS + x0];
        float s0 = 0.f, s1 = 0.f, s2 = 0.f, s3 = 0.f;
        #pragma unroll
        for (int k = 0; k < 20; k += 4) {
            s0 += row[k];     s1 += row[k + 1];
            s2 += row[k + 2]; s3 += row[k + 3];
        }
        float s = (s0 + s1) + (s2 + s3) + row[20];
        hrow[0] = s;
        #pragma unroll
        for (int i = 1; i < SEG; ++i) {
            s += row[i + 20] - row[i - 1];
            hrow[i] = s;
        }
    }
    __syncthreads();

    // ---- Vertical 21-sums + residual: 64 cols x 8 segs = 512 tasks
    // (exactly 2 rounds of 256). Stores coalesced 64-wide. ----
    for (int t = tid; t < TILE * SEG; t += 256) {
        const int col = t & 63;
        const int y0  = (t >> 6) * SEG;
        float s0 = 0.f, s1 = 0.f, s2 = 0.f, s3 = 0.f;
        #pragma unroll
        for (int k = 0; k < 20; k += 4) {
            s0 += hs[(y0 + k)     * HSS + col];
            s1 += hs[(y0 + k + 1) * HSS + col];
            s2 += hs[(y0 + k + 2) * HSS + col];
            s3 += hs[(y0 + k + 3) * HSS + col];
        }
        float s = (s0 + s1) + (s2 + s3) + hs[(y0 + 20) * HSS + col];
        float* dptr = dst + (ty * TILE + y0) * WW + tx * TILE + col;
        float center = lm[(y0 + HALO) * LMS + col + HALO];
        dptr[0] = fmaf(-w, s, center);
        #pragma unroll
        for (int i = 1; i < SEG; ++i) {
            s += hs[(y0 + 20 + i) * HSS + col] - hs[(y0 + i - 1) * HSS + col];
            center = lm[(y0 + i + HALO) * LMS + col + HALO];
            dptr[i * WW] = fmaf(-w, s, center);
        }
    }
}

extern "C" void kernel_launch(void* const* d_in, const int* in_sizes, int n_in,
                              void* d_out, int out_size, void* d_ws, size_t ws_size,
                              hipStream_t stream)
{
    const float* in   = (const float*)d_in[0];
    const float* kern = (const float*)d_in[1];
    float*       out  = (float*)d_out;

    dim3 grid(WW / TILE, HH / TILE, 32 * 6);
    spectral_residual_fused_kernel<<<grid, 256, 0, stream>>>(in, kern, out);
}

// Round 5
// 203.674 us; speedup vs baseline: 1.2680x; 1.2680x over previous
//
#include <hip/hip_runtime.h>
#include <math.h>

// fft_coeffs: (32, 6, 384, 384) fp32; kernel: (3,1,21,21) fp32 uniform box.
//   out ch 0-2: log1p(mag) - boxfilter21x21(log1p(mag)) * w_c  (zero-padded)
//   out ch 3-5: copy.
// R5: fp16 LDS (26.5 KB -> 6 blocks/CU) + float4-vectorized staging.
#define HH    384
#define WW    384
#define TILE   64
#define HALO   10
#define KW     21
#define LDIM   84          // TILE + 2*HALO
#define LMS    90          // lm stride in fp16 (45 words, odd -> conflict-free)
#define HSS    68          // hs stride in fp16 (136 B, 8B-aligned rows)
#define SEG     8
#define PLANE 147456       // 384*384

__global__ __launch_bounds__(256)
void spectral_residual_fused_kernel(const float* __restrict__ in,
                                    const float* __restrict__ kern,
                                    float* __restrict__ out)
{
    __shared__ _Float16 lm[LDIM * LMS];   // 84x90 fp16 log tile  (15.1 KB)
    __shared__ _Float16 hs[LDIM * HSS];   // 84x68 fp16 horiz sums (11.4 KB)

    const int tid   = threadIdx.x;
    const int tx    = blockIdx.x;
    const int ty    = blockIdx.y;
    const int plane = blockIdx.z;          // n*6 + c
    const int c     = plane % 6;
    const size_t plane_off = (size_t)plane * PLANE;

    if (c >= 3) {
        // Phase channels: contiguous 16 KB float4 copy per block.
        const float4* __restrict__ s = (const float4*)(in + plane_off);
        float4*       __restrict__ d = (float4*)(out + plane_off);
        const int base = (ty * 6 + tx) * 1024;
        #pragma unroll
        for (int i = 0; i < 4; ++i) {
            int e = base + i * 256 + tid;
            d[e] = s[e];
        }
        return;
    }

    const float w = kern[c * (KW * KW)];   // uniform weight (1/441)

    const float* __restrict__ src = in  + plane_off;
    float*       __restrict__ dst = out + plane_off;

    const int gy0 = ty * TILE - HALO;
    const int gxa = tx * TILE - HALO - 2;  // float4-aligned left edge (== 2 mod 4 shift)

    // ---- Stage log(1+mag) halo tile as fp16, float4 global loads.
    // 84 rows x 22 float4 = 1848 tasks. Stored col = gx - gxa in [0,88);
    // logical x_local = stored - 2. Zero-pad OOB (log1p(0)=0 so log after
    // zero-fill is correct). ----
    for (int t = tid; t < LDIM * 22; t += 256) {
        const int r  = t / 22;
        const int j  = t - r * 22;
        const int gy = gy0 + r;
        const int gx = gxa + 4 * j;
        float4 v = make_float4(0.f, 0.f, 0.f, 0.f);
        if ((unsigned)gy < HH) {
            const float* rp = src + gy * WW;
            if ((unsigned)gx <= WW - 4) {
                v = *(const float4*)(rp + gx);
            } else {
                if ((unsigned)(gx + 0) < WW) v.x = rp[gx + 0];
                if ((unsigned)(gx + 1) < WW) v.y = rp[gx + 1];
                if ((unsigned)(gx + 2) < WW) v.z = rp[gx + 2];
                if ((unsigned)(gx + 3) < WW) v.w = rp[gx + 3];
            }
        }
        union { _Float16 h[4]; unsigned int u[2]; } p;
        p.h[0] = (_Float16)__logf(1.0f + v.x);
        p.h[1] = (_Float16)__logf(1.0f + v.y);
        p.h[2] = (_Float16)__logf(1.0f + v.z);
        p.h[3] = (_Float16)__logf(1.0f + v.w);
        unsigned int* lp = (unsigned int*)&lm[r * LMS + 4 * j];
        lp[0] = p.u[0];
        lp[1] = p.u[1];
    }
    __syncthreads();

    // ---- Horizontal 21-sums, 8-output sliding segments (fp32 accum).
    // 84 rows x 8 segs = 672 tasks. ----
    for (int t = tid; t < LDIM * SEG; t += 256) {
        const int r  = t >> 3;
        const int x0 = (t & 7) * 8;
        const _Float16* row = &lm[r * LMS + 2 + x0];
        float s0 = 0.f, s1 = 0.f, s2 = 0.f, s3 = 0.f;
        #pragma unroll
        for (int k = 0; k < 20; k += 4) {
            s0 += (float)row[k];     s1 += (float)row[k + 1];
            s2 += (float)row[k + 2]; s3 += (float)row[k + 3];
        }
        float s = (s0 + s1) + (s2 + s3) + (float)row[20];
        union { _Float16 h[8]; unsigned int u[4]; } o;
        o.h[0] = (_Float16)s;
        #pragma unroll
        for (int i = 1; i < SEG; ++i) {
            s += (float)row[i + 20] - (float)row[i - 1];
            o.h[i] = (_Float16)s;
        }
        unsigned int* hp = (unsigned int*)&hs[r * HSS + x0];
        #pragma unroll
        for (int i = 0; i < 4; ++i) hp[i] = o.u[i];
    }
    __syncthreads();

    // ---- Vertical 21-sums + residual; 64 cols x 8 segs = 512 tasks,
    // coalesced 64-wide row stores. ----
    for (int t = tid; t < TILE * SEG; t += 256) {
        const int col = t & 63;
        const int y0  = (t >> 6) * SEG;
        float s0 = 0.f, s1 = 0.f, s2 = 0.f, s3 = 0.f;
        #pragma unroll
        for (int k = 0; k < 20; k += 4) {
            s0 += (float)hs[(y0 + k)     * HSS + col];
            s1 += (float)hs[(y0 + k + 1) * HSS + col];
            s2 += (float)hs[(y0 + k + 2) * HSS + col];
            s3 += (float)hs[(y0 + k + 3) * HSS + col];
        }
        float s = (s0 + s1) + (s2 + s3) + (float)hs[(y0 + 20) * HSS + col];
        float* dptr = dst + (ty * TILE + y0) * WW + tx * TILE + col;
        float center = (float)lm[(y0 + HALO) * LMS + 12 + col];
        dptr[0] = fmaf(-w, s, center);
        #pragma unroll
        for (int i = 1; i < SEG; ++i) {
            s += (float)hs[(y0 + 20 + i) * HSS + col]
               - (float)hs[(y0 + i - 1) * HSS + col];
            center = (float)lm[(y0 + i + HALO) * LMS + 12 + col];
            dptr[i * WW] = fmaf(-w, s, center);
        }
    }
}

extern "C" void kernel_launch(void* const* d_in, const int* in_sizes, int n_in,
                              void* d_out, int out_size, void* d_ws, size_t ws_size,
                              hipStream_t stream)
{
    const float* in   = (const float*)d_in[0];
    const float* kern = (const float*)d_in[1];
    float*       out  = (float*)d_out;

    dim3 grid(WW / TILE, HH / TILE, 32 * 6);
    spectral_residual_fused_kernel<<<grid, 256, 0, stream>>>(in, kern, out);
}